// Round 1
// baseline (3031.489 us; speedup 1.0000x reference)
//
#include <hip/hip_runtime.h>
#include <cstdint>
#include <cstddef>

#define HIDDEN 128
#define N_NODES_C 50000

constexpr int GEMM_ROWS = 32;

// C[M,128] = act( (RELU_IN ? relu(A) : A)[M,K] @ W[K,128] (+ bias) )
template<int K, bool RELU_OUT, bool RELU_IN, bool BIAS>
__global__ __launch_bounds__(256) void gemm_bias(
    const float* __restrict__ A, const float* __restrict__ W,
    const float* __restrict__ bias, float* __restrict__ C, int M)
{
    __shared__ float As[GEMM_ROWS][K];
    const int tile = blockIdx.x * GEMM_ROWS;

    constexpr int TOT4 = GEMM_ROWS * K / 4;
    for (int i = threadIdx.x; i < TOT4; i += 256) {
        int r  = i / (K / 4);
        int kk = (i % (K / 4)) * 4;
        int grow = tile + r;
        float4 v = make_float4(0.f, 0.f, 0.f, 0.f);
        if (grow < M) v = *(const float4*)(A + (size_t)grow * K + kk);
        if (RELU_IN) {
            v.x = fmaxf(v.x, 0.f); v.y = fmaxf(v.y, 0.f);
            v.z = fmaxf(v.z, 0.f); v.w = fmaxf(v.w, 0.f);
        }
        *(float4*)(&As[r][kk]) = v;
    }
    __syncthreads();

    const int cg = (threadIdx.x & 31) * 4;   // 4 consecutive output cols
    const int rg = (threadIdx.x >> 5) * 4;   // 4 consecutive rows of the tile
    float acc[4][4] = {};

    for (int k = 0; k < K; k += 4) {
        float av[4][4];
        #pragma unroll
        for (int r = 0; r < 4; ++r)
            *(float4*)&av[r][0] = *(const float4*)(&As[rg + r][k]);
        #pragma unroll
        for (int kk = 0; kk < 4; ++kk) {
            float4 w = *(const float4*)(W + (size_t)(k + kk) * HIDDEN + cg);
            #pragma unroll
            for (int r = 0; r < 4; ++r) {
                float a = av[r][kk];
                acc[r][0] = fmaf(a, w.x, acc[r][0]);
                acc[r][1] = fmaf(a, w.y, acc[r][1]);
                acc[r][2] = fmaf(a, w.z, acc[r][2]);
                acc[r][3] = fmaf(a, w.w, acc[r][3]);
            }
        }
    }

    float4 b4 = make_float4(0.f, 0.f, 0.f, 0.f);
    if (BIAS) b4 = *(const float4*)(bias + cg);
    #pragma unroll
    for (int r = 0; r < 4; ++r) {
        int grow = tile + rg + r;
        if (grow >= M) break;
        float4 o;
        o.x = acc[r][0] + b4.x;
        o.y = acc[r][1] + b4.y;
        o.z = acc[r][2] + b4.z;
        o.w = acc[r][3] + b4.w;
        if (RELU_OUT) {
            o.x = fmaxf(o.x, 0.f); o.y = fmaxf(o.y, 0.f);
            o.z = fmaxf(o.z, 0.f); o.w = fmaxf(o.w, 0.f);
        }
        *(float4*)(C + (size_t)grow * HIDDEN + cg) = o;
    }
}

// One edge per 32 lanes; each lane owns 4 of the 128 channels.
__global__ __launch_bounds__(256) void edge_kernel(
    const int* __restrict__ ei, int E,
    const float* __restrict__ Amat, const float* __restrict__ Bmat,
    const float* __restrict__ Lmat,
    const float* __restrict__ hid_b, const float* __restrict__ pw,
    const float* __restrict__ pb, float* __restrict__ out)
{
    int gid = blockIdx.x * 256 + threadIdx.x;
    int e = gid >> 5;
    if (e >= E) return;
    int lane = threadIdx.x & 31;
    int c = lane * 4;

    int s = ei[e];        // edge_index[0] = source j
    int d = ei[E + e];    // edge_index[1] = target i

    float4 ai = *(const float4*)(Amat + (size_t)d * HIDDEN + c);
    float4 bj = *(const float4*)(Bmat + (size_t)s * HIDDEN + c);
    float4 hb = *(const float4*)(hid_b + c);
    float4 w4 = *(const float4*)(pw + c);

    float h0 = fmaxf(ai.x + bj.x + hb.x, 0.f);
    float h1 = fmaxf(ai.y + bj.y + hb.y, 0.f);
    float h2 = fmaxf(ai.z + bj.z + hb.z, 0.f);
    float h3 = fmaxf(ai.w + bj.w + hb.w, 0.f);

    float part = h0 * w4.x + h1 * w4.y + h2 * w4.z + h3 * w4.w;
    #pragma unroll
    for (int off = 16; off > 0; off >>= 1)
        part += __shfl_xor(part, off);

    float pick = 1.f / (1.f + __expf(-(part + pb[0])));

    float4 l4 = *(const float4*)(Lmat + (size_t)s * HIDDEN + c);
    float* op = out + (size_t)d * HIDDEN + c;
    unsafeAtomicAdd(op + 0, pick * l4.x);
    unsafeAtomicAdd(op + 1, pick * l4.y);
    unsafeAtomicAdd(op + 2, pick * l4.z);
    unsafeAtomicAdd(op + 3, pick * l4.w);
}

// out[M,2] = H[M,128] @ Wc[128,2] + bc
__global__ __launch_bounds__(256) void classifier_kernel(
    const float* __restrict__ H, const float* __restrict__ Wc,
    const float* __restrict__ bc, float* __restrict__ out, int M)
{
    int m = blockIdx.x * 256 + threadIdx.x;
    if (m >= M) return;
    float a0 = bc[0], a1 = bc[1];
    for (int k = 0; k < HIDDEN; k += 4) {
        float4 h = *(const float4*)(H + (size_t)m * HIDDEN + k);
        a0 = fmaf(h.x, Wc[(k + 0) * 2 + 0], a0);
        a1 = fmaf(h.x, Wc[(k + 0) * 2 + 1], a1);
        a0 = fmaf(h.y, Wc[(k + 1) * 2 + 0], a0);
        a1 = fmaf(h.y, Wc[(k + 1) * 2 + 1], a1);
        a0 = fmaf(h.z, Wc[(k + 2) * 2 + 0], a0);
        a1 = fmaf(h.z, Wc[(k + 2) * 2 + 1], a1);
        a0 = fmaf(h.w, Wc[(k + 3) * 2 + 0], a0);
        a1 = fmaf(h.w, Wc[(k + 3) * 2 + 1], a1);
    }
    out[(size_t)m * 2 + 0] = a0;
    out[(size_t)m * 2 + 1] = a1;
}

extern "C" void kernel_launch(void* const* d_in, const int* in_sizes, int n_in,
                              void* d_out, int out_size, void* d_ws, size_t ws_size,
                              hipStream_t stream)
{
    const float* x      = (const float*)d_in[0];
    const int*   ei     = (const int*)d_in[1];
    const float* enc_w  = (const float*)d_in[2];
    const float* enc_b  = (const float*)d_in[3];
    const float* lin1_w = (const float*)d_in[4];
    const float* lin1_b = (const float*)d_in[5];
    const float* p1a_w  = (const float*)d_in[6];
    const float* p1a_b  = (const float*)d_in[7];
    const float* p1b_w  = (const float*)d_in[8];
    const float* p1b_b  = (const float*)d_in[9];
    const float* lin2_w = (const float*)d_in[10];
    const float* lin2_b = (const float*)d_in[11];
    const float* p2a_w  = (const float*)d_in[12];
    const float* p2a_b  = (const float*)d_in[13];
    const float* p2b_w  = (const float*)d_in[14];
    const float* p2b_b  = (const float*)d_in[15];
    const float* cls_w  = (const float*)d_in[16];
    const float* cls_b  = (const float*)d_in[17];

    const int M = N_NODES_C;
    const int E = in_sizes[1] / 2;

    float* W0 = (float*)d_ws;                 // h0 -> h1 acc -> h2 acc
    float* W1 = W0 + (size_t)M * HIDDEN;      // A  (dst-side pre-act)
    float* W2 = W1 + (size_t)M * HIDDEN;      // B  (src-side pre-act)
    float* W3 = W2 + (size_t)M * HIDDEN;      // L  (lin message)

    const size_t hbytes = (size_t)M * HIDDEN * sizeof(float);
    const int ggrid = (M + GEMM_ROWS - 1) / GEMM_ROWS;
    const int egrid = (E * 32 + 255) / 256;
    const int cgrid = (M + 255) / 256;
    dim3 blk(256);

    // encoder: h0 = relu(x @ enc_w + enc_b)
    gemm_bias<256, true, false, true><<<ggrid, blk, 0, stream>>>(x, enc_w, enc_b, W0, M);

    // ---- layer 1 precompute (per-node) ----
    gemm_bias<128, false, false, false><<<ggrid, blk, 0, stream>>>(W0, p1a_w,                nullptr, W1, M);
    gemm_bias<128, false, false, false><<<ggrid, blk, 0, stream>>>(W0, p1a_w + 128 * HIDDEN, nullptr, W2, M);
    gemm_bias<128, false, false, true ><<<ggrid, blk, 0, stream>>>(W0, lin1_w, lin1_b,                W3, M);

    hipMemsetAsync(W0, 0, hbytes, stream);
    edge_kernel<<<egrid, blk, 0, stream>>>(ei, E, W1, W2, W3, p1a_b, p1b_w, p1b_b, W0);

    // ---- layer 2 precompute (input = relu(h1)) ----
    gemm_bias<128, false, true, false><<<ggrid, blk, 0, stream>>>(W0, p2a_w,                nullptr, W1, M);
    gemm_bias<128, false, true, false><<<ggrid, blk, 0, stream>>>(W0, p2a_w + 128 * HIDDEN, nullptr, W2, M);
    gemm_bias<128, false, true, true ><<<ggrid, blk, 0, stream>>>(W0, lin2_w, lin2_b,               W3, M);

    hipMemsetAsync(W0, 0, hbytes, stream);
    edge_kernel<<<egrid, blk, 0, stream>>>(ei, E, W1, W2, W3, p2a_b, p2b_w, p2b_b, W0);

    // classifier: out = h2 @ cls_w + cls_b   (no relu after layer 2 per reference)
    classifier_kernel<<<cgrid, blk, 0, stream>>>(W0, cls_w, cls_b, (float*)d_out, M);
}

// Round 2
// 700.505 us; speedup vs baseline: 4.3276x; 4.3276x over previous
//
#include <hip/hip_runtime.h>
#include <cstdint>
#include <cstddef>

#define HIDDEN 128
#define N_NODES_C 50000

constexpr int GEMM_ROWS = 32;

// C[M,128] = act( (RELU_IN ? relu(A) : A)[M,K] @ W[K,128] (+ bias) )
template<int K, bool RELU_OUT, bool RELU_IN, bool BIAS>
__global__ __launch_bounds__(256) void gemm_bias(
    const float* __restrict__ A, const float* __restrict__ W,
    const float* __restrict__ bias, float* __restrict__ C, int M)
{
    __shared__ float As[GEMM_ROWS][K];
    const int tile = blockIdx.x * GEMM_ROWS;

    constexpr int TOT4 = GEMM_ROWS * K / 4;
    for (int i = threadIdx.x; i < TOT4; i += 256) {
        int r  = i / (K / 4);
        int kk = (i % (K / 4)) * 4;
        int grow = tile + r;
        float4 v = make_float4(0.f, 0.f, 0.f, 0.f);
        if (grow < M) v = *(const float4*)(A + (size_t)grow * K + kk);
        if (RELU_IN) {
            v.x = fmaxf(v.x, 0.f); v.y = fmaxf(v.y, 0.f);
            v.z = fmaxf(v.z, 0.f); v.w = fmaxf(v.w, 0.f);
        }
        *(float4*)(&As[r][kk]) = v;
    }
    __syncthreads();

    const int cg = (threadIdx.x & 31) * 4;   // 4 consecutive output cols
    const int rg = (threadIdx.x >> 5) * 4;   // 4 consecutive rows of the tile
    float acc[4][4] = {};

    for (int k = 0; k < K; k += 4) {
        float av[4][4];
        #pragma unroll
        for (int r = 0; r < 4; ++r)
            *(float4*)&av[r][0] = *(const float4*)(&As[rg + r][k]);
        #pragma unroll
        for (int kk = 0; kk < 4; ++kk) {
            float4 w = *(const float4*)(W + (size_t)(k + kk) * HIDDEN + cg);
            #pragma unroll
            for (int r = 0; r < 4; ++r) {
                float a = av[r][kk];
                acc[r][0] = fmaf(a, w.x, acc[r][0]);
                acc[r][1] = fmaf(a, w.y, acc[r][1]);
                acc[r][2] = fmaf(a, w.z, acc[r][2]);
                acc[r][3] = fmaf(a, w.w, acc[r][3]);
            }
        }
    }

    float4 b4 = make_float4(0.f, 0.f, 0.f, 0.f);
    if (BIAS) b4 = *(const float4*)(bias + cg);
    #pragma unroll
    for (int r = 0; r < 4; ++r) {
        int grow = tile + rg + r;
        if (grow >= M) break;
        float4 o;
        o.x = acc[r][0] + b4.x;
        o.y = acc[r][1] + b4.y;
        o.z = acc[r][2] + b4.z;
        o.w = acc[r][3] + b4.w;
        if (RELU_OUT) {
            o.x = fmaxf(o.x, 0.f); o.y = fmaxf(o.y, 0.f);
            o.z = fmaxf(o.z, 0.f); o.w = fmaxf(o.w, 0.f);
        }
        *(float4*)(C + (size_t)grow * HIDDEN + cg) = o;
    }
}

// ---- CSR build ----
__global__ __launch_bounds__(256) void hist_kernel(
    const int* __restrict__ ei, int E, int* __restrict__ deg)
{
    int e = blockIdx.x * 256 + threadIdx.x;
    if (e >= E) return;
    atomicAdd(&deg[ei[E + e]], 1);
}

// single-block exclusive scan: offs[0..M] from deg[0..M-1]
__global__ __launch_bounds__(1024) void scan_kernel(
    const int* __restrict__ deg, int* __restrict__ offs, int M)
{
    __shared__ int part[1024];
    const int t = threadIdx.x;
    const int chunk = (M + 1023) / 1024;
    const int lo = t * chunk;
    const int hi = min(lo + chunk, M);
    int s = 0;
    for (int i = lo; i < hi; ++i) s += deg[i];
    part[t] = s;
    __syncthreads();
    for (int off = 1; off < 1024; off <<= 1) {
        int v = (t >= off) ? part[t - off] : 0;
        __syncthreads();
        part[t] += v;
        __syncthreads();
    }
    int excl = (t == 0) ? 0 : part[t - 1];
    for (int i = lo; i < hi; ++i) { offs[i] = excl; excl += deg[i]; }
    if (lo < M && hi == M) offs[M] = excl;
}

__global__ __launch_bounds__(256) void scatter_kernel(
    const int* __restrict__ ei, int E, const int* __restrict__ offs,
    int* __restrict__ cursor, int* __restrict__ srcs)
{
    int e = blockIdx.x * 256 + threadIdx.x;
    if (e >= E) return;
    int d = ei[E + e];
    int pos = offs[d] + atomicAdd(&cursor[d], 1);
    srcs[pos] = ei[e];
}

// One 64-lane wave per dst node; lane owns 2 channels.
// out[d] = sum_e sigmoid(dot(relu(A[d]+B[s]+hb), pw)+pb) * L[s]
// NOTE: out may alias A (row d of A is read only by this wave, before the write).
__global__ __launch_bounds__(256) void gather_kernel(
    const int* __restrict__ offs, const int* __restrict__ srcs,
    const float* __restrict__ Amat, const float* __restrict__ Bmat,
    const float* __restrict__ Lmat,
    const float* __restrict__ hid_b, const float* __restrict__ pw,
    const float* __restrict__ pb, float* __restrict__ out, int M)
{
    int node = blockIdx.x * 4 + (threadIdx.x >> 6);
    if (node >= M) return;
    const int lane = threadIdx.x & 63;
    const int c = lane * 2;

    float2 a2  = *(const float2*)(Amat + (size_t)node * HIDDEN + c);
    float2 hb2 = *(const float2*)(hid_b + c);
    float2 pw2 = *(const float2*)(pw + c);
    const float pb0 = pb[0];

    float2 acc = make_float2(0.f, 0.f);
    int k   = offs[node];
    int end = offs[node + 1];

    for (; k < end; ++k) {
        int s = srcs[k];
        float2 b2 = *(const float2*)(Bmat + (size_t)s * HIDDEN + c);
        float2 l2 = *(const float2*)(Lmat + (size_t)s * HIDDEN + c);
        float h0 = fmaxf(a2.x + b2.x + hb2.x, 0.f);
        float h1 = fmaxf(a2.y + b2.y + hb2.y, 0.f);
        float part = h0 * pw2.x + h1 * pw2.y;
        #pragma unroll
        for (int off = 32; off > 0; off >>= 1)
            part += __shfl_xor(part, off);
        float pick = 1.f / (1.f + __expf(-(part + pb0)));
        acc.x = fmaf(pick, l2.x, acc.x);
        acc.y = fmaf(pick, l2.y, acc.y);
    }
    *(float2*)(out + (size_t)node * HIDDEN + c) = acc;
}

// out[M,2] = H[M,128] @ Wc[128,2] + bc
__global__ __launch_bounds__(256) void classifier_kernel(
    const float* __restrict__ H, const float* __restrict__ Wc,
    const float* __restrict__ bc, float* __restrict__ out, int M)
{
    int m = blockIdx.x * 256 + threadIdx.x;
    if (m >= M) return;
    float a0 = bc[0], a1 = bc[1];
    for (int k = 0; k < HIDDEN; k += 4) {
        float4 h = *(const float4*)(H + (size_t)m * HIDDEN + k);
        a0 = fmaf(h.x, Wc[(k + 0) * 2 + 0], a0);
        a1 = fmaf(h.x, Wc[(k + 0) * 2 + 1], a1);
        a0 = fmaf(h.y, Wc[(k + 1) * 2 + 0], a0);
        a1 = fmaf(h.y, Wc[(k + 1) * 2 + 1], a1);
        a0 = fmaf(h.z, Wc[(k + 2) * 2 + 0], a0);
        a1 = fmaf(h.z, Wc[(k + 2) * 2 + 1], a1);
        a0 = fmaf(h.w, Wc[(k + 3) * 2 + 0], a0);
        a1 = fmaf(h.w, Wc[(k + 3) * 2 + 1], a1);
    }
    out[(size_t)m * 2 + 0] = a0;
    out[(size_t)m * 2 + 1] = a1;
}

extern "C" void kernel_launch(void* const* d_in, const int* in_sizes, int n_in,
                              void* d_out, int out_size, void* d_ws, size_t ws_size,
                              hipStream_t stream)
{
    const float* x      = (const float*)d_in[0];
    const int*   ei     = (const int*)d_in[1];
    const float* enc_w  = (const float*)d_in[2];
    const float* enc_b  = (const float*)d_in[3];
    const float* lin1_w = (const float*)d_in[4];
    const float* lin1_b = (const float*)d_in[5];
    const float* p1a_w  = (const float*)d_in[6];
    const float* p1a_b  = (const float*)d_in[7];
    const float* p1b_w  = (const float*)d_in[8];
    const float* p1b_b  = (const float*)d_in[9];
    const float* lin2_w = (const float*)d_in[10];
    const float* lin2_b = (const float*)d_in[11];
    const float* p2a_w  = (const float*)d_in[12];
    const float* p2a_b  = (const float*)d_in[13];
    const float* p2b_w  = (const float*)d_in[14];
    const float* p2b_b  = (const float*)d_in[15];
    const float* cls_w  = (const float*)d_in[16];
    const float* cls_b  = (const float*)d_in[17];

    const int M = N_NODES_C;
    const int E = in_sizes[1] / 2;

    float* W0 = (float*)d_ws;                 // h0, then A2, then h2
    float* W1 = W0 + (size_t)M * HIDDEN;      // A1, then h1
    float* W2 = W1 + (size_t)M * HIDDEN;      // B
    float* W3 = W2 + (size_t)M * HIDDEN;      // L
    int* deg  = (int*)(W3 + (size_t)M * HIDDEN);  // M ints (reused as cursor)
    int* offs = deg + M;                          // M+1 ints
    int* srcs = offs + M + 1;                     // E ints

    const int ggrid = (M + GEMM_ROWS - 1) / GEMM_ROWS;
    const int egrid = (E + 255) / 256;
    const int ngrid = (M + 3) / 4;      // 4 waves (nodes) per 256-thread block
    const int cgrid = (M + 255) / 256;
    dim3 blk(256);

    // ---- CSR build (shared by both layers; dst buckets) ----
    hipMemsetAsync(deg, 0, (size_t)M * sizeof(int), stream);
    hist_kernel<<<egrid, blk, 0, stream>>>(ei, E, deg);
    scan_kernel<<<1, 1024, 0, stream>>>(deg, offs, M);
    hipMemsetAsync(deg, 0, (size_t)M * sizeof(int), stream);  // deg -> cursor
    scatter_kernel<<<egrid, blk, 0, stream>>>(ei, E, offs, deg, srcs);

    // encoder: h0 = relu(x @ enc_w + enc_b)  -> W0
    gemm_bias<256, true, false, true><<<ggrid, blk, 0, stream>>>(x, enc_w, enc_b, W0, M);

    // ---- layer 1 per-node precompute (from W0) ----
    gemm_bias<128, false, false, false><<<ggrid, blk, 0, stream>>>(W0, p1a_w,                nullptr, W1, M);
    gemm_bias<128, false, false, false><<<ggrid, blk, 0, stream>>>(W0, p1a_w + 128 * HIDDEN, nullptr, W2, M);
    gemm_bias<128, false, false, true ><<<ggrid, blk, 0, stream>>>(W0, lin1_w, lin1_b,                W3, M);

    // gather: h1 -> W1 (overwrites A1 in place; safe, row-private)
    gather_kernel<<<ngrid, blk, 0, stream>>>(offs, srcs, W1, W2, W3,
                                             p1a_b, p1b_w, p1b_b, W1, M);

    // ---- layer 2 per-node precompute (input = relu(W1)) ----
    gemm_bias<128, false, true, false><<<ggrid, blk, 0, stream>>>(W1, p2a_w,                nullptr, W0, M);
    gemm_bias<128, false, true, false><<<ggrid, blk, 0, stream>>>(W1, p2a_w + 128 * HIDDEN, nullptr, W2, M);
    gemm_bias<128, false, true, true ><<<ggrid, blk, 0, stream>>>(W1, lin2_w, lin2_b,               W3, M);

    // gather: h2 -> W0
    gather_kernel<<<ngrid, blk, 0, stream>>>(offs, srcs, W0, W2, W3,
                                             p2a_b, p2b_w, p2b_b, W0, M);

    // classifier: out = h2 @ cls_w + cls_b
    classifier_kernel<<<cgrid, blk, 0, stream>>>(W0, cls_w, cls_b, (float*)d_out, M);
}

// Round 3
// 627.855 us; speedup vs baseline: 4.8283x; 1.1157x over previous
//
#include <hip/hip_runtime.h>
#include <cstdint>
#include <cstddef>

#define HIDDEN 128
#define N_NODES_C 50000

constexpr int GEMM_ROWS = 32;

// C[M,128] = act( A[M,K] @ W[K,128] (+ bias) )   (encoder only)
template<int K, bool RELU_OUT, bool RELU_IN, bool BIAS>
__global__ __launch_bounds__(256) void gemm_bias(
    const float* __restrict__ A, const float* __restrict__ W,
    const float* __restrict__ bias, float* __restrict__ C, int M)
{
    __shared__ float As[GEMM_ROWS][K];
    const int tile = blockIdx.x * GEMM_ROWS;

    constexpr int TOT4 = GEMM_ROWS * K / 4;
    for (int i = threadIdx.x; i < TOT4; i += 256) {
        int r  = i / (K / 4);
        int kk = (i % (K / 4)) * 4;
        int grow = tile + r;
        float4 v = make_float4(0.f, 0.f, 0.f, 0.f);
        if (grow < M) v = *(const float4*)(A + (size_t)grow * K + kk);
        if (RELU_IN) {
            v.x = fmaxf(v.x, 0.f); v.y = fmaxf(v.y, 0.f);
            v.z = fmaxf(v.z, 0.f); v.w = fmaxf(v.w, 0.f);
        }
        *(float4*)(&As[r][kk]) = v;
    }
    __syncthreads();

    const int cg = (threadIdx.x & 31) * 4;
    const int rg = (threadIdx.x >> 5) * 4;
    float acc[4][4] = {};

    for (int k = 0; k < K; k += 4) {
        float av[4][4];
        #pragma unroll
        for (int r = 0; r < 4; ++r)
            *(float4*)&av[r][0] = *(const float4*)(&As[rg + r][k]);
        #pragma unroll
        for (int kk = 0; kk < 4; ++kk) {
            float4 w = *(const float4*)(W + (size_t)(k + kk) * HIDDEN + cg);
            #pragma unroll
            for (int r = 0; r < 4; ++r) {
                float a = av[r][kk];
                acc[r][0] = fmaf(a, w.x, acc[r][0]);
                acc[r][1] = fmaf(a, w.y, acc[r][1]);
                acc[r][2] = fmaf(a, w.z, acc[r][2]);
                acc[r][3] = fmaf(a, w.w, acc[r][3]);
            }
        }
    }

    float4 b4 = make_float4(0.f, 0.f, 0.f, 0.f);
    if (BIAS) b4 = *(const float4*)(bias + cg);
    #pragma unroll
    for (int r = 0; r < 4; ++r) {
        int grow = tile + rg + r;
        if (grow >= M) break;
        float4 o;
        o.x = acc[r][0] + b4.x;
        o.y = acc[r][1] + b4.y;
        o.z = acc[r][2] + b4.z;
        o.w = acc[r][3] + b4.w;
        if (RELU_OUT) {
            o.x = fmaxf(o.x, 0.f); o.y = fmaxf(o.y, 0.f);
            o.z = fmaxf(o.z, 0.f); o.w = fmaxf(o.w, 0.f);
        }
        *(float4*)(C + (size_t)grow * HIDDEN + cg) = o;
    }
}

// Fused per-layer node precompute: from h compute
//   WA = h' @ paw[:128], WB = h' @ paw[128:], WL = h' @ linw + linb
// where h' = relu(h) if RELU_IN. One LDS h-tile shared by all 3 outputs.
template<bool RELU_IN>
__global__ __launch_bounds__(256) void fused3_kernel(
    const float* __restrict__ h, const float* __restrict__ paw,
    const float* __restrict__ linw, const float* __restrict__ linb,
    float* __restrict__ WA, float* __restrict__ WB, float* __restrict__ WL,
    int M)
{
    __shared__ float As[GEMM_ROWS][HIDDEN];
    const int tile = blockIdx.x * GEMM_ROWS;

    constexpr int TOT4 = GEMM_ROWS * HIDDEN / 4;
    for (int i = threadIdx.x; i < TOT4; i += 256) {
        int r  = i >> 5;            // HIDDEN/4 == 32 float4 per row
        int kk = (i & 31) * 4;
        int grow = tile + r;
        float4 v = make_float4(0.f, 0.f, 0.f, 0.f);
        if (grow < M) v = *(const float4*)(h + (size_t)grow * HIDDEN + kk);
        if (RELU_IN) {
            v.x = fmaxf(v.x, 0.f); v.y = fmaxf(v.y, 0.f);
            v.z = fmaxf(v.z, 0.f); v.w = fmaxf(v.w, 0.f);
        }
        *(float4*)(&As[r][kk]) = v;
    }
    __syncthreads();

    const int cg = (threadIdx.x & 31) * 4;
    const int rg = (threadIdx.x >> 5) * 4;

    #pragma unroll
    for (int m = 0; m < 3; ++m) {   // compile-time index (no scratch)
        const float* W = (m == 0) ? paw : (m == 1) ? paw + HIDDEN * HIDDEN : linw;
        float* Cp      = (m == 0) ? WA  : (m == 1) ? WB                    : WL;

        float acc[4][4] = {};
        for (int k = 0; k < HIDDEN; k += 4) {
            float av[4][4];
            #pragma unroll
            for (int r = 0; r < 4; ++r)
                *(float4*)&av[r][0] = *(const float4*)(&As[rg + r][k]);
            #pragma unroll
            for (int kk = 0; kk < 4; ++kk) {
                float4 w = *(const float4*)(W + (size_t)(k + kk) * HIDDEN + cg);
                #pragma unroll
                for (int r = 0; r < 4; ++r) {
                    float a = av[r][kk];
                    acc[r][0] = fmaf(a, w.x, acc[r][0]);
                    acc[r][1] = fmaf(a, w.y, acc[r][1]);
                    acc[r][2] = fmaf(a, w.z, acc[r][2]);
                    acc[r][3] = fmaf(a, w.w, acc[r][3]);
                }
            }
        }

        float4 b4 = make_float4(0.f, 0.f, 0.f, 0.f);
        if (m == 2) b4 = *(const float4*)(linb + cg);
        #pragma unroll
        for (int r = 0; r < 4; ++r) {
            int grow = tile + rg + r;
            if (grow >= M) break;
            float4 o;
            o.x = acc[r][0] + b4.x;
            o.y = acc[r][1] + b4.y;
            o.z = acc[r][2] + b4.z;
            o.w = acc[r][3] + b4.w;
            *(float4*)(Cp + (size_t)grow * HIDDEN + cg) = o;
        }
    }
}

// ---- CSR build ----
__global__ __launch_bounds__(256) void hist_kernel(
    const int* __restrict__ ei, int E, int* __restrict__ deg)
{
    int e = blockIdx.x * 256 + threadIdx.x;
    if (e >= E) return;
    atomicAdd(&deg[ei[E + e]], 1);
}

__global__ __launch_bounds__(1024) void scan_kernel(
    const int* __restrict__ deg, int* __restrict__ offs, int M)
{
    __shared__ int part[1024];
    const int t = threadIdx.x;
    const int chunk = (M + 1023) / 1024;
    const int lo = t * chunk;
    const int hi = min(lo + chunk, M);
    int s = 0;
    for (int i = lo; i < hi; ++i) s += deg[i];
    part[t] = s;
    __syncthreads();
    for (int off = 1; off < 1024; off <<= 1) {
        int v = (t >= off) ? part[t - off] : 0;
        __syncthreads();
        part[t] += v;
        __syncthreads();
    }
    int excl = (t == 0) ? 0 : part[t - 1];
    for (int i = lo; i < hi; ++i) { offs[i] = excl; excl += deg[i]; }
    if (lo < M && hi == M) offs[M] = excl;
}

__global__ __launch_bounds__(256) void scatter_kernel(
    const int* __restrict__ ei, int E, const int* __restrict__ offs,
    int* __restrict__ cursor, int* __restrict__ srcs)
{
    int e = blockIdx.x * 256 + threadIdx.x;
    if (e >= E) return;
    int d = ei[E + e];
    int pos = offs[d] + atomicAdd(&cursor[d], 1);
    srcs[pos] = ei[e];
}

// One 64-lane wave per dst node, TWO edges per iteration:
// half-wave (32 lanes) per edge, lane owns 4 channels.
// out[d] = sum_e sigmoid(dot(relu(A[d]+hb+B[s]), pw)+pb) * L[s]
__global__ __launch_bounds__(256) void gather_kernel(
    const int* __restrict__ offs, const int* __restrict__ srcs,
    const float* __restrict__ Amat, const float* __restrict__ Bmat,
    const float* __restrict__ Lmat,
    const float* __restrict__ hid_b, const float* __restrict__ pw,
    const float* __restrict__ pb, float* __restrict__ out, int M)
{
    int node = blockIdx.x * 4 + (threadIdx.x >> 6);
    if (node >= M) return;
    const int lane = threadIdx.x & 63;
    const int half = lane >> 5;
    const int c = (lane & 31) * 4;

    float4 a4  = *(const float4*)(Amat + (size_t)node * HIDDEN + c);
    float4 hb4 = *(const float4*)(hid_b + c);
    a4.x += hb4.x; a4.y += hb4.y; a4.z += hb4.z; a4.w += hb4.w;
    float4 pw4 = *(const float4*)(pw + c);
    const float pb0 = pb[0];

    float4 acc = make_float4(0.f, 0.f, 0.f, 0.f);
    int k   = offs[node];
    int end = offs[node + 1];

    for (; k + 1 < end; k += 2) {
        int s = srcs[k + half];
        float4 b4 = *(const float4*)(Bmat + (size_t)s * HIDDEN + c);
        float4 l4 = *(const float4*)(Lmat + (size_t)s * HIDDEN + c);
        float h0 = fmaxf(a4.x + b4.x, 0.f);
        float h1 = fmaxf(a4.y + b4.y, 0.f);
        float h2 = fmaxf(a4.z + b4.z, 0.f);
        float h3 = fmaxf(a4.w + b4.w, 0.f);
        float part = h0 * pw4.x + h1 * pw4.y + h2 * pw4.z + h3 * pw4.w;
        part += __shfl_xor(part, 16);
        part += __shfl_xor(part, 8);
        part += __shfl_xor(part, 4);
        part += __shfl_xor(part, 2);
        part += __shfl_xor(part, 1);
        float pick = 1.f / (1.f + __expf(-(part + pb0)));
        acc.x = fmaf(pick, l4.x, acc.x);
        acc.y = fmaf(pick, l4.y, acc.y);
        acc.z = fmaf(pick, l4.z, acc.z);
        acc.w = fmaf(pick, l4.w, acc.w);
    }
    if (k < end) {                        // odd tail: both halves read same edge
        int s = srcs[k];
        float4 b4 = *(const float4*)(Bmat + (size_t)s * HIDDEN + c);
        float4 l4 = *(const float4*)(Lmat + (size_t)s * HIDDEN + c);
        float h0 = fmaxf(a4.x + b4.x, 0.f);
        float h1 = fmaxf(a4.y + b4.y, 0.f);
        float h2 = fmaxf(a4.z + b4.z, 0.f);
        float h3 = fmaxf(a4.w + b4.w, 0.f);
        float part = h0 * pw4.x + h1 * pw4.y + h2 * pw4.z + h3 * pw4.w;
        part += __shfl_xor(part, 16);
        part += __shfl_xor(part, 8);
        part += __shfl_xor(part, 4);
        part += __shfl_xor(part, 2);
        part += __shfl_xor(part, 1);
        float pick = 1.f / (1.f + __expf(-(part + pb0)));
        if (half) pick = 0.f;             // upper half is a duplicate
        acc.x = fmaf(pick, l4.x, acc.x);
        acc.y = fmaf(pick, l4.y, acc.y);
        acc.z = fmaf(pick, l4.z, acc.z);
        acc.w = fmaf(pick, l4.w, acc.w);
    }

    // combine the two half-wave accumulators (lane c <-> lane c+32)
    acc.x += __shfl_xor(acc.x, 32);
    acc.y += __shfl_xor(acc.y, 32);
    acc.z += __shfl_xor(acc.z, 32);
    acc.w += __shfl_xor(acc.w, 32);
    if (half == 0)
        *(float4*)(out + (size_t)node * HIDDEN + c) = acc;
}

// out[M,2] = H[M,128] @ Wc[128,2] + bc
__global__ __launch_bounds__(256) void classifier_kernel(
    const float* __restrict__ H, const float* __restrict__ Wc,
    const float* __restrict__ bc, float* __restrict__ out, int M)
{
    int m = blockIdx.x * 256 + threadIdx.x;
    if (m >= M) return;
    float a0 = bc[0], a1 = bc[1];
    for (int k = 0; k < HIDDEN; k += 4) {
        float4 h = *(const float4*)(H + (size_t)m * HIDDEN + k);
        a0 = fmaf(h.x, Wc[(k + 0) * 2 + 0], a0);
        a1 = fmaf(h.x, Wc[(k + 0) * 2 + 1], a1);
        a0 = fmaf(h.y, Wc[(k + 1) * 2 + 0], a0);
        a1 = fmaf(h.y, Wc[(k + 1) * 2 + 1], a1);
        a0 = fmaf(h.z, Wc[(k + 2) * 2 + 0], a0);
        a1 = fmaf(h.z, Wc[(k + 2) * 2 + 1], a1);
        a0 = fmaf(h.w, Wc[(k + 3) * 2 + 0], a0);
        a1 = fmaf(h.w, Wc[(k + 3) * 2 + 1], a1);
    }
    out[(size_t)m * 2 + 0] = a0;
    out[(size_t)m * 2 + 1] = a1;
}

extern "C" void kernel_launch(void* const* d_in, const int* in_sizes, int n_in,
                              void* d_out, int out_size, void* d_ws, size_t ws_size,
                              hipStream_t stream)
{
    const float* x      = (const float*)d_in[0];
    const int*   ei     = (const int*)d_in[1];
    const float* enc_w  = (const float*)d_in[2];
    const float* enc_b  = (const float*)d_in[3];
    const float* lin1_w = (const float*)d_in[4];
    const float* lin1_b = (const float*)d_in[5];
    const float* p1a_w  = (const float*)d_in[6];
    const float* p1a_b  = (const float*)d_in[7];
    const float* p1b_w  = (const float*)d_in[8];
    const float* p1b_b  = (const float*)d_in[9];
    const float* lin2_w = (const float*)d_in[10];
    const float* lin2_b = (const float*)d_in[11];
    const float* p2a_w  = (const float*)d_in[12];
    const float* p2a_b  = (const float*)d_in[13];
    const float* p2b_w  = (const float*)d_in[14];
    const float* p2b_b  = (const float*)d_in[15];
    const float* cls_w  = (const float*)d_in[16];
    const float* cls_b  = (const float*)d_in[17];

    const int M = N_NODES_C;
    const int E = in_sizes[1] / 2;

    float* W0 = (float*)d_ws;                 // h0, then A2(h2 site)
    float* W1 = W0 + (size_t)M * HIDDEN;      // A1 -> h1
    float* W2 = W1 + (size_t)M * HIDDEN;      // B
    float* W3 = W2 + (size_t)M * HIDDEN;      // L
    int* deg  = (int*)(W3 + (size_t)M * HIDDEN);  // M ints (reused as cursor)
    int* offs = deg + M;                          // M+1 ints
    int* srcs = offs + M + 1;                     // E ints

    const int ggrid = (M + GEMM_ROWS - 1) / GEMM_ROWS;
    const int egrid = (E + 255) / 256;
    const int ngrid = (M + 3) / 4;
    const int cgrid = (M + 255) / 256;
    dim3 blk(256);

    // ---- CSR build (dst buckets; shared by both layers) ----
    hipMemsetAsync(deg, 0, (size_t)M * sizeof(int), stream);
    hist_kernel<<<egrid, blk, 0, stream>>>(ei, E, deg);
    scan_kernel<<<1, 1024, 0, stream>>>(deg, offs, M);
    hipMemsetAsync(deg, 0, (size_t)M * sizeof(int), stream);
    scatter_kernel<<<egrid, blk, 0, stream>>>(ei, E, offs, deg, srcs);

    // encoder: h0 = relu(x @ enc_w + enc_b) -> W0
    gemm_bias<256, true, false, true><<<ggrid, blk, 0, stream>>>(x, enc_w, enc_b, W0, M);

    // layer 1 precompute: A1->W1, B->W2, L->W3  (input h0, no relu-in)
    fused3_kernel<false><<<ggrid, blk, 0, stream>>>(W0, p1a_w, lin1_w, lin1_b,
                                                    W1, W2, W3, M);
    // gather: h1 -> W1 (in-place over A1; rows are wave-private)
    gather_kernel<<<ngrid, blk, 0, stream>>>(offs, srcs, W1, W2, W3,
                                             p1a_b, p1b_w, p1b_b, W1, M);

    // layer 2 precompute: input relu(h1)=relu(W1); A2->W0, B->W2, L->W3
    fused3_kernel<true><<<ggrid, blk, 0, stream>>>(W1, p2a_w, lin2_w, lin2_b,
                                                   W0, W2, W3, M);
    // gather: h2 -> W0
    gather_kernel<<<ngrid, blk, 0, stream>>>(offs, srcs, W0, W2, W3,
                                             p2a_b, p2b_w, p2b_b, W0, M);

    // classifier: out = h2 @ cls_w + cls_b
    classifier_kernel<<<cgrid, blk, 0, stream>>>(W0, cls_w, cls_b, (float*)d_out, M);
}

// Round 4
// 441.280 us; speedup vs baseline: 6.8698x; 1.4228x over previous
//
#include <hip/hip_runtime.h>
#include <cstdint>
#include <cstddef>

#define HIDDEN 128
#define N_NODES_C 50000

typedef short bf16x8 __attribute__((ext_vector_type(8)));   // 8 bf16 in 4 VGPRs
typedef unsigned short u16x8 __attribute__((ext_vector_type(8)));
typedef float f32x4 __attribute__((ext_vector_type(4)));

__device__ inline unsigned short f2b(float x) {   // fp32 -> bf16 RNE
    union { float f; unsigned int u; } v; v.f = x;
    unsigned int r = v.u + 0x7FFFu + ((v.u >> 16) & 1u);
    return (unsigned short)(r >> 16);
}
__device__ inline float b2f(unsigned short h) {
    union { unsigned int u; float f; } v; v.u = ((unsigned int)h) << 16;
    return v.f;
}

// ---- one-time weight prep: transposed bf16 copies (W^T[n][k] = W[k][n]) ----
__global__ __launch_bounds__(256) void prep_weights(
    const float* __restrict__ enc_w, const float* __restrict__ p1a_w,
    const float* __restrict__ lin1_w, const float* __restrict__ p2a_w,
    const float* __restrict__ lin2_w,
    unsigned short* __restrict__ encT,
    unsigned short* __restrict__ A1T, unsigned short* __restrict__ B1T,
    unsigned short* __restrict__ L1T,
    unsigned short* __restrict__ A2T, unsigned short* __restrict__ B2T,
    unsigned short* __restrict__ L2T)
{
    const int b = blockIdx.x, t = threadIdx.x;
    if (b < 2) {           // encT: [128][256] from enc_w [256][128]
        for (int i = t; i < 64 * 256; i += 256) {
            int n = b * 64 + (i >> 8);
            int k = i & 255;
            encT[n * 256 + k] = f2b(enc_w[k * 128 + n]);
        }
    } else {
        const float* src; unsigned short* dst;
        switch (b) {
            case 2: src = p1a_w;              dst = A1T; break;
            case 3: src = p1a_w + 128 * 128;  dst = B1T; break;
            case 4: src = lin1_w;             dst = L1T; break;
            case 5: src = p2a_w;              dst = A2T; break;
            case 6: src = p2a_w + 128 * 128;  dst = B2T; break;
            default: src = lin2_w;            dst = L2T; break;
        }
        for (int i = t; i < 128 * 128; i += 256) {
            int n = i >> 7, k = i & 127;
            dst[n * 128 + k] = f2b(src[k * 128 + n]);
        }
    }
}

// ---- encoder: h0 = relu(x @ enc_w + enc_b), bf16 out. MFMA 16x16x32. ----
// 4 waves/block, 16 rows/wave -> 64 rows/block.
__global__ __launch_bounds__(256) void enc_mfma(
    const float* __restrict__ x, const unsigned short* __restrict__ encT,
    const float* __restrict__ enc_b, unsigned short* __restrict__ h0, int M)
{
    const int wave = threadIdx.x >> 6, lane = threadIdx.x & 63;
    const int rowBase = blockIdx.x * 64 + wave * 16;
    const int sl = lane & 15, kg = lane >> 4;
    const int row_a = rowBase + sl;

    f32x4 acc[8] = {};
    for (int ks = 0; ks < 8; ++ks) {
        const int k0 = ks * 32 + kg * 8;
        bf16x8 a = {};
        if (row_a < M) {
            const float* xp = x + (size_t)row_a * 256 + k0;
            float4 f0 = *(const float4*)xp;
            float4 f1 = *(const float4*)(xp + 4);
            a[0] = (short)f2b(f0.x); a[1] = (short)f2b(f0.y);
            a[2] = (short)f2b(f0.z); a[3] = (short)f2b(f0.w);
            a[4] = (short)f2b(f1.x); a[5] = (short)f2b(f1.y);
            a[6] = (short)f2b(f1.z); a[7] = (short)f2b(f1.w);
        }
        #pragma unroll
        for (int ct = 0; ct < 8; ++ct) {
            bf16x8 bfr = *(const bf16x8*)(encT + (size_t)(ct * 16 + sl) * 256 + k0);
            acc[ct] = __builtin_amdgcn_mfma_f32_16x16x32_bf16(a, bfr, acc[ct], 0, 0, 0);
        }
    }
    #pragma unroll
    for (int ct = 0; ct < 8; ++ct) {
        const int col = ct * 16 + sl;
        const float eb = enc_b[col];
        #pragma unroll
        for (int r = 0; r < 4; ++r) {
            const int row = rowBase + kg * 4 + r;
            if (row < M)
                h0[(size_t)row * 128 + col] = f2b(fmaxf(acc[ct][r] + eb, 0.f));
        }
    }
}

// ---- fused per-layer node precompute: A = h@AT', B = h@BT', L = h@LT'+linb ----
__global__ __launch_bounds__(256) void fused3_mfma(
    const unsigned short* __restrict__ h,
    const unsigned short* __restrict__ AT, const unsigned short* __restrict__ BT,
    const unsigned short* __restrict__ LT, const float* __restrict__ linb,
    unsigned short* __restrict__ outA, unsigned short* __restrict__ outB,
    unsigned short* __restrict__ outL, int M)
{
    const int wave = threadIdx.x >> 6, lane = threadIdx.x & 63;
    const int rowBase = blockIdx.x * 64 + wave * 16;
    const int sl = lane & 15, kg = lane >> 4;
    const int row_a = rowBase + sl;

    bf16x8 afr[4];
    #pragma unroll
    for (int ks = 0; ks < 4; ++ks) {
        if (row_a < M)
            afr[ks] = *(const bf16x8*)(h + (size_t)row_a * 128 + ks * 32 + kg * 8);
        else
            afr[ks] = bf16x8{};
    }

    #pragma unroll
    for (int m = 0; m < 3; ++m) {               // compile-time select (no scratch)
        const unsigned short* WT = (m == 0) ? AT : (m == 1) ? BT : LT;
        unsigned short* op       = (m == 0) ? outA : (m == 1) ? outB : outL;

        f32x4 acc[8] = {};
        #pragma unroll
        for (int ks = 0; ks < 4; ++ks) {
            const int k0 = ks * 32 + kg * 8;
            #pragma unroll
            for (int ct = 0; ct < 8; ++ct) {
                bf16x8 bfr = *(const bf16x8*)(WT + (size_t)(ct * 16 + sl) * 128 + k0);
                acc[ct] = __builtin_amdgcn_mfma_f32_16x16x32_bf16(afr[ks], bfr, acc[ct], 0, 0, 0);
            }
        }
        #pragma unroll
        for (int ct = 0; ct < 8; ++ct) {
            const int col = ct * 16 + sl;
            const float lb = (m == 2) ? linb[col] : 0.f;
            #pragma unroll
            for (int r = 0; r < 4; ++r) {
                const int row = rowBase + kg * 4 + r;
                if (row < M)
                    op[(size_t)row * 128 + col] = f2b(acc[ct][r] + lb);
            }
        }
    }
}

// ---- CSR build ----
__global__ __launch_bounds__(256) void hist_kernel(
    const int* __restrict__ ei, int E, int* __restrict__ deg)
{
    int e = blockIdx.x * 256 + threadIdx.x;
    if (e >= E) return;
    atomicAdd(&deg[ei[E + e]], 1);
}

__global__ __launch_bounds__(1024) void scan_kernel(
    const int* __restrict__ deg, int* __restrict__ offs, int M)
{
    __shared__ int part[1024];
    const int t = threadIdx.x;
    const int chunk = (M + 1023) / 1024;
    const int lo = t * chunk;
    const int hi = min(lo + chunk, M);
    int s = 0;
    for (int i = lo; i < hi; ++i) s += deg[i];
    part[t] = s;
    __syncthreads();
    for (int off = 1; off < 1024; off <<= 1) {
        int v = (t >= off) ? part[t - off] : 0;
        __syncthreads();
        part[t] += v;
        __syncthreads();
    }
    int excl = (t == 0) ? 0 : part[t - 1];
    for (int i = lo; i < hi; ++i) { offs[i] = excl; excl += deg[i]; }
    if (lo < M && hi == M) offs[M] = excl;
}

__global__ __launch_bounds__(256) void scatter_kernel(
    const int* __restrict__ ei, int E, const int* __restrict__ offs,
    int* __restrict__ cursor, int* __restrict__ srcs)
{
    int e = blockIdx.x * 256 + threadIdx.x;
    if (e >= E) return;
    int d = ei[E + e];
    int pos = offs[d] + atomicAdd(&cursor[d], 1);
    srcs[pos] = ei[e];
}

// ---- gather: one wave per dst node, one edge per 16-lane group (4 in flight).
// out[d] = sum_e sigmoid(dot(relu(A[d]+hb+B[s]), pw)+pb) * L[s]; bf16 rows.
template<bool RELU_OUT>
__global__ __launch_bounds__(256) void gather_bf16(
    const int* __restrict__ offs, const int* __restrict__ srcs,
    const unsigned short* __restrict__ Amat, const unsigned short* __restrict__ Bmat,
    const unsigned short* __restrict__ Lmat,
    const float* __restrict__ hid_b, const float* __restrict__ pw,
    const float* __restrict__ pb, unsigned short* __restrict__ out, int M)
{
    const int node = blockIdx.x * 4 + (threadIdx.x >> 6);
    if (node >= M) return;
    const int lane = threadIdx.x & 63;
    const int grp = lane >> 4;          // which edge of the 4 in flight
    const int sl  = lane & 15;
    const int c8  = sl * 8;             // 8 channels per lane

    float a[8], w[8];
    {
        u16x8 av = *(const u16x8*)(Amat + (size_t)node * 128 + c8);
        float4 h0 = *(const float4*)(hid_b + c8);
        float4 h1 = *(const float4*)(hid_b + c8 + 4);
        a[0] = b2f(av[0]) + h0.x; a[1] = b2f(av[1]) + h0.y;
        a[2] = b2f(av[2]) + h0.z; a[3] = b2f(av[3]) + h0.w;
        a[4] = b2f(av[4]) + h1.x; a[5] = b2f(av[5]) + h1.y;
        a[6] = b2f(av[6]) + h1.z; a[7] = b2f(av[7]) + h1.w;
        float4 p0 = *(const float4*)(pw + c8);
        float4 p1 = *(const float4*)(pw + c8 + 4);
        w[0] = p0.x; w[1] = p0.y; w[2] = p0.z; w[3] = p0.w;
        w[4] = p1.x; w[5] = p1.y; w[6] = p1.z; w[7] = p1.w;
    }
    const float pb0 = pb[0];
    float acc[8] = {};

    const int start = offs[node], end = offs[node + 1];
    for (int k = start; k < end; k += 4) {
        const int idx = k + grp;
        const bool valid = idx < end;
        const int s = valid ? srcs[idx] : 0;
        u16x8 bv = *(const u16x8*)(Bmat + (size_t)s * 128 + c8);
        u16x8 lv = *(const u16x8*)(Lmat + (size_t)s * 128 + c8);

        float part = 0.f;
        #pragma unroll
        for (int j = 0; j < 8; ++j)
            part += fmaxf(a[j] + b2f(bv[j]), 0.f) * w[j];
        part += __shfl_xor(part, 8);
        part += __shfl_xor(part, 4);
        part += __shfl_xor(part, 2);
        part += __shfl_xor(part, 1);

        float pick = valid ? 1.f / (1.f + __expf(-(part + pb0))) : 0.f;
        #pragma unroll
        for (int j = 0; j < 8; ++j)
            acc[j] = fmaf(pick, b2f(lv[j]), acc[j]);
    }

    #pragma unroll
    for (int j = 0; j < 8; ++j) acc[j] += __shfl_xor(acc[j], 16);
    #pragma unroll
    for (int j = 0; j < 8; ++j) acc[j] += __shfl_xor(acc[j], 32);

    if (grp == 0) {
        u16x8 o;
        #pragma unroll
        for (int j = 0; j < 8; ++j) {
            float v = acc[j];
            if (RELU_OUT) v = fmaxf(v, 0.f);
            o[j] = f2b(v);
        }
        *(u16x8*)(out + (size_t)node * 128 + c8) = o;
    }
}

// ---- classifier: out[M,2] = h2(bf16) @ cls_w + cls_b (fp32) ----
__global__ __launch_bounds__(256) void classifier_bf16(
    const unsigned short* __restrict__ H, const float* __restrict__ Wc,
    const float* __restrict__ bc, float* __restrict__ out, int M)
{
    int m = blockIdx.x * 256 + threadIdx.x;
    if (m >= M) return;
    float a0 = bc[0], a1 = bc[1];
    for (int k = 0; k < 128; k += 8) {
        u16x8 h = *(const u16x8*)(H + (size_t)m * 128 + k);
        #pragma unroll
        for (int j = 0; j < 8; ++j) {
            float hv = b2f(h[j]);
            a0 = fmaf(hv, Wc[(k + j) * 2 + 0], a0);
            a1 = fmaf(hv, Wc[(k + j) * 2 + 1], a1);
        }
    }
    out[(size_t)m * 2 + 0] = a0;
    out[(size_t)m * 2 + 1] = a1;
}

extern "C" void kernel_launch(void* const* d_in, const int* in_sizes, int n_in,
                              void* d_out, int out_size, void* d_ws, size_t ws_size,
                              hipStream_t stream)
{
    const float* x      = (const float*)d_in[0];
    const int*   ei     = (const int*)d_in[1];
    const float* enc_w  = (const float*)d_in[2];
    const float* enc_b  = (const float*)d_in[3];
    const float* lin1_w = (const float*)d_in[4];
    const float* lin1_b = (const float*)d_in[5];
    const float* p1a_w  = (const float*)d_in[6];
    const float* p1a_b  = (const float*)d_in[7];
    const float* p1b_w  = (const float*)d_in[8];
    const float* p1b_b  = (const float*)d_in[9];
    const float* lin2_w = (const float*)d_in[10];
    const float* lin2_b = (const float*)d_in[11];
    const float* p2a_w  = (const float*)d_in[12];
    const float* p2a_b  = (const float*)d_in[13];
    const float* p2b_w  = (const float*)d_in[14];
    const float* p2b_b  = (const float*)d_in[15];
    const float* cls_w  = (const float*)d_in[16];
    const float* cls_b  = (const float*)d_in[17];

    const int M = N_NODES_C;
    const int E = in_sizes[1] / 2;
    const size_t HS = (size_t)M * HIDDEN;       // ushorts per node matrix

    unsigned short* Hb0 = (unsigned short*)d_ws;   // h0 -> A2 -> h2
    unsigned short* HA  = Hb0 + HS;                // A1 -> relu(h1)
    unsigned short* HB  = HA + HS;                 // B
    unsigned short* HL  = HB + HS;                 // L
    unsigned short* encT = HL + HS;                // [128][256]
    unsigned short* A1T = encT + 128 * 256;        // [128][128] each
    unsigned short* B1T = A1T + 128 * 128;
    unsigned short* L1T = B1T + 128 * 128;
    unsigned short* A2T = L1T + 128 * 128;
    unsigned short* B2T = A2T + 128 * 128;
    unsigned short* L2T = B2T + 128 * 128;
    int* deg  = (int*)(L2T + 128 * 128);           // M (reused as cursor)
    int* offs = deg + M;                           // M+1
    int* srcs = offs + M + 1;                      // E

    const int ggrid = (M + 63) / 64;               // 64 rows per block
    const int egrid = (E + 255) / 256;
    const int ngrid = (M + 3) / 4;
    const int cgrid = (M + 255) / 256;
    dim3 blk(256);

    // weight prep (independent)
    prep_weights<<<8, blk, 0, stream>>>(enc_w, p1a_w, lin1_w, p2a_w, lin2_w,
                                        encT, A1T, B1T, L1T, A2T, B2T, L2T);

    // CSR build (dst buckets, shared by both layers)
    hipMemsetAsync(deg, 0, (size_t)M * sizeof(int), stream);
    hist_kernel<<<egrid, blk, 0, stream>>>(ei, E, deg);
    scan_kernel<<<1, 1024, 0, stream>>>(deg, offs, M);
    hipMemsetAsync(deg, 0, (size_t)M * sizeof(int), stream);
    scatter_kernel<<<egrid, blk, 0, stream>>>(ei, E, offs, deg, srcs);

    // encoder
    enc_mfma<<<ggrid, blk, 0, stream>>>(x, encT, enc_b, Hb0, M);

    // layer 1
    fused3_mfma<<<ggrid, blk, 0, stream>>>(Hb0, A1T, B1T, L1T, lin1_b,
                                           HA, HB, HL, M);
    gather_bf16<true><<<ngrid, blk, 0, stream>>>(offs, srcs, HA, HB, HL,
                                                 p1a_b, p1b_w, p1b_b, HA, M);

    // layer 2 (input = relu(h1) already applied at gather store)
    fused3_mfma<<<ggrid, blk, 0, stream>>>(HA, A2T, B2T, L2T, lin2_b,
                                           Hb0, HB, HL, M);
    gather_bf16<false><<<ngrid, blk, 0, stream>>>(offs, srcs, Hb0, HB, HL,
                                                  p2a_b, p2b_w, p2b_b, Hb0, M);

    // classifier
    classifier_bf16<<<cgrid, blk, 0, stream>>>(Hb0, cls_w, cls_b, (float*)d_out, M);
}

// Round 5
// 373.775 us; speedup vs baseline: 8.1105x; 1.1806x over previous
//
#include <hip/hip_runtime.h>
#include <cstdint>
#include <cstddef>

#define HIDDEN 128
#define N_NODES_C 50000

typedef short bf16x8 __attribute__((ext_vector_type(8)));   // 8 bf16 in 4 VGPRs
typedef unsigned short u16x8 __attribute__((ext_vector_type(8)));
typedef float f32x4 __attribute__((ext_vector_type(4)));

__device__ inline unsigned short f2b(float x) {   // fp32 -> bf16 RNE
    union { float f; unsigned int u; } v; v.f = x;
    unsigned int r = v.u + 0x7FFFu + ((v.u >> 16) & 1u);
    return (unsigned short)(r >> 16);
}
__device__ inline float b2f(unsigned short h) {
    union { unsigned int u; float f; } v; v.u = ((unsigned int)h) << 16;
    return v.f;
}

// ---- one-time weight prep: transposed bf16 copies (W^T[n][k] = W[k][n]) ----
__global__ __launch_bounds__(256) void prep_weights(
    const float* __restrict__ enc_w, const float* __restrict__ p1a_w,
    const float* __restrict__ lin1_w, const float* __restrict__ p2a_w,
    const float* __restrict__ lin2_w,
    unsigned short* __restrict__ encT,
    unsigned short* __restrict__ A1T, unsigned short* __restrict__ B1T,
    unsigned short* __restrict__ L1T,
    unsigned short* __restrict__ A2T, unsigned short* __restrict__ B2T,
    unsigned short* __restrict__ L2T)
{
    const int b = blockIdx.x, t = threadIdx.x;
    if (b < 2) {           // encT: [128][256] from enc_w [256][128]
        for (int i = t; i < 64 * 256; i += 256) {
            int n = b * 64 + (i >> 8);
            int k = i & 255;
            encT[n * 256 + k] = f2b(enc_w[k * 128 + n]);
        }
    } else {
        const float* src; unsigned short* dst;
        switch (b) {
            case 2: src = p1a_w;              dst = A1T; break;
            case 3: src = p1a_w + 128 * 128;  dst = B1T; break;
            case 4: src = lin1_w;             dst = L1T; break;
            case 5: src = p2a_w;              dst = A2T; break;
            case 6: src = p2a_w + 128 * 128;  dst = B2T; break;
            default: src = lin2_w;            dst = L2T; break;
        }
        for (int i = t; i < 128 * 128; i += 256) {
            int n = i >> 7, k = i & 127;
            dst[n * 128 + k] = f2b(src[k * 128 + n]);
        }
    }
}

// ---- encoder: h0 = relu(x @ enc_w + enc_b), bf16 out. MFMA 16x16x32. ----
__global__ __launch_bounds__(256) void enc_mfma(
    const float* __restrict__ x, const unsigned short* __restrict__ encT,
    const float* __restrict__ enc_b, unsigned short* __restrict__ h0, int M)
{
    const int wave = threadIdx.x >> 6, lane = threadIdx.x & 63;
    const int rowBase = blockIdx.x * 64 + wave * 16;
    const int sl = lane & 15, kg = lane >> 4;
    const int row_a = rowBase + sl;

    f32x4 acc[8] = {};
    for (int ks = 0; ks < 8; ++ks) {
        const int k0 = ks * 32 + kg * 8;
        bf16x8 a = {};
        if (row_a < M) {
            const float* xp = x + (size_t)row_a * 256 + k0;
            float4 f0 = *(const float4*)xp;
            float4 f1 = *(const float4*)(xp + 4);
            a[0] = (short)f2b(f0.x); a[1] = (short)f2b(f0.y);
            a[2] = (short)f2b(f0.z); a[3] = (short)f2b(f0.w);
            a[4] = (short)f2b(f1.x); a[5] = (short)f2b(f1.y);
            a[6] = (short)f2b(f1.z); a[7] = (short)f2b(f1.w);
        }
        #pragma unroll
        for (int ct = 0; ct < 8; ++ct) {
            bf16x8 bfr = *(const bf16x8*)(encT + (size_t)(ct * 16 + sl) * 256 + k0);
            acc[ct] = __builtin_amdgcn_mfma_f32_16x16x32_bf16(a, bfr, acc[ct], 0, 0, 0);
        }
    }
    #pragma unroll
    for (int ct = 0; ct < 8; ++ct) {
        const int col = ct * 16 + sl;
        const float eb = enc_b[col];
        #pragma unroll
        for (int r = 0; r < 4; ++r) {
            const int row = rowBase + kg * 4 + r;
            if (row < M)
                h0[(size_t)row * 128 + col] = f2b(fmaxf(acc[ct][r] + eb, 0.f));
        }
    }
}

// ---- fused per-layer node precompute: A = h@AT', B = h@BT', L = h@LT'+linb ----
__global__ __launch_bounds__(256) void fused3_mfma(
    const unsigned short* __restrict__ h,
    const unsigned short* __restrict__ AT, const unsigned short* __restrict__ BT,
    const unsigned short* __restrict__ LT, const float* __restrict__ linb,
    unsigned short* __restrict__ outA, unsigned short* __restrict__ outB,
    unsigned short* __restrict__ outL, int M)
{
    const int wave = threadIdx.x >> 6, lane = threadIdx.x & 63;
    const int rowBase = blockIdx.x * 64 + wave * 16;
    const int sl = lane & 15, kg = lane >> 4;
    const int row_a = rowBase + sl;

    bf16x8 afr[4];
    #pragma unroll
    for (int ks = 0; ks < 4; ++ks) {
        if (row_a < M)
            afr[ks] = *(const bf16x8*)(h + (size_t)row_a * 128 + ks * 32 + kg * 8);
        else
            afr[ks] = bf16x8{};
    }

    #pragma unroll
    for (int m = 0; m < 3; ++m) {               // compile-time select (no scratch)
        const unsigned short* WT = (m == 0) ? AT : (m == 1) ? BT : LT;
        unsigned short* op       = (m == 0) ? outA : (m == 1) ? outB : outL;

        f32x4 acc[8] = {};
        #pragma unroll
        for (int ks = 0; ks < 4; ++ks) {
            const int k0 = ks * 32 + kg * 8;
            #pragma unroll
            for (int ct = 0; ct < 8; ++ct) {
                bf16x8 bfr = *(const bf16x8*)(WT + (size_t)(ct * 16 + sl) * 128 + k0);
                acc[ct] = __builtin_amdgcn_mfma_f32_16x16x32_bf16(afr[ks], bfr, acc[ct], 0, 0, 0);
            }
        }
        #pragma unroll
        for (int ct = 0; ct < 8; ++ct) {
            const int col = ct * 16 + sl;
            const float lb = (m == 2) ? linb[col] : 0.f;
            #pragma unroll
            for (int r = 0; r < 4; ++r) {
                const int row = rowBase + kg * 4 + r;
                if (row < M)
                    op[(size_t)row * 128 + col] = f2b(acc[ct][r] + lb);
            }
        }
    }
}

// ---- CSR build ----
__global__ __launch_bounds__(256) void hist_kernel(
    const int* __restrict__ ei, int E, int* __restrict__ deg)
{
    int e = blockIdx.x * 256 + threadIdx.x;
    if (e >= E) return;
    atomicAdd(&deg[ei[E + e]], 1);
}

// pass 1: per-1024-tile exclusive scan; block sums out
__global__ __launch_bounds__(256) void scan_blocks(
    const int* __restrict__ deg, int* __restrict__ offs,
    int* __restrict__ bsums, int M)
{
    __shared__ int part[256];
    const int t = threadIdx.x;
    const int base = blockIdx.x * 1024 + t * 4;

    int v0 = 0, v1 = 0, v2 = 0, v3 = 0;
    if (base + 3 < M) {
        int4 d = *(const int4*)(deg + base);
        v0 = d.x; v1 = d.y; v2 = d.z; v3 = d.w;
    } else {
        if (base + 0 < M) v0 = deg[base + 0];
        if (base + 1 < M) v1 = deg[base + 1];
        if (base + 2 < M) v2 = deg[base + 2];
    }
    part[t] = v0 + v1 + v2 + v3;
    __syncthreads();
    for (int off = 1; off < 256; off <<= 1) {
        int u = (t >= off) ? part[t - off] : 0;
        __syncthreads();
        part[t] += u;
        __syncthreads();
    }
    const int excl = (t == 0) ? 0 : part[t - 1];
    if (t == 255) bsums[blockIdx.x] = part[255];

    if (base + 0 < M) offs[base + 0] = excl;
    if (base + 1 < M) offs[base + 1] = excl + v0;
    if (base + 2 < M) offs[base + 2] = excl + v0 + v1;
    if (base + 3 < M) offs[base + 3] = excl + v0 + v1 + v2;
}

// pass 2: one wave scans the <=64 block sums -> exclusive; offs[M] = total
__global__ __launch_bounds__(64) void scan_sums(
    int* __restrict__ bsums, int* __restrict__ offs, int nb, int M)
{
    const int t = threadIdx.x;
    const int mine = (t < nb) ? bsums[t] : 0;
    int v = mine;
    #pragma unroll
    for (int off = 1; off < 64; off <<= 1) {
        int u = __shfl_up(v, off);
        if (t >= off) v += u;
    }
    if (t < nb) bsums[t] = v - mine;   // exclusive
    if (t == 63) offs[M] = v;          // grand total (E)
}

// pass 3: add block offsets
__global__ __launch_bounds__(256) void scan_add(
    int* __restrict__ offs, const int* __restrict__ bsums, int M)
{
    const int base = blockIdx.x * 1024 + threadIdx.x * 4;
    const int add = bsums[blockIdx.x];
    if (add == 0) return;
    if (base + 3 < M) {
        int4 d = *(int4*)(offs + base);
        d.x += add; d.y += add; d.z += add; d.w += add;
        *(int4*)(offs + base) = d;
    } else {
        for (int j = 0; j < 4; ++j)
            if (base + j < M) offs[base + j] += add;
    }
}

__global__ __launch_bounds__(256) void scatter_kernel(
    const int* __restrict__ ei, int E, const int* __restrict__ offs,
    int* __restrict__ cursor, int* __restrict__ srcs)
{
    int e = blockIdx.x * 256 + threadIdx.x;
    if (e >= E) return;
    int d = ei[E + e];
    int pos = offs[d] + atomicAdd(&cursor[d], 1);
    srcs[pos] = ei[e];
}

// ---- gather: one wave per dst node, one edge per 16-lane group (4 in flight).
template<bool RELU_OUT>
__global__ __launch_bounds__(256) void gather_bf16(
    const int* __restrict__ offs, const int* __restrict__ srcs,
    const unsigned short* __restrict__ Amat, const unsigned short* __restrict__ Bmat,
    const unsigned short* __restrict__ Lmat,
    const float* __restrict__ hid_b, const float* __restrict__ pw,
    const float* __restrict__ pb, unsigned short* __restrict__ out, int M)
{
    const int node = blockIdx.x * 4 + (threadIdx.x >> 6);
    if (node >= M) return;
    const int lane = threadIdx.x & 63;
    const int grp = lane >> 4;          // which edge of the 4 in flight
    const int sl  = lane & 15;
    const int c8  = sl * 8;             // 8 channels per lane

    float a[8], w[8];
    {
        u16x8 av = *(const u16x8*)(Amat + (size_t)node * 128 + c8);
        float4 h0 = *(const float4*)(hid_b + c8);
        float4 h1 = *(const float4*)(hid_b + c8 + 4);
        a[0] = b2f(av[0]) + h0.x; a[1] = b2f(av[1]) + h0.y;
        a[2] = b2f(av[2]) + h0.z; a[3] = b2f(av[3]) + h0.w;
        a[4] = b2f(av[4]) + h1.x; a[5] = b2f(av[5]) + h1.y;
        a[6] = b2f(av[6]) + h1.z; a[7] = b2f(av[7]) + h1.w;
        float4 p0 = *(const float4*)(pw + c8);
        float4 p1 = *(const float4*)(pw + c8 + 4);
        w[0] = p0.x; w[1] = p0.y; w[2] = p0.z; w[3] = p0.w;
        w[4] = p1.x; w[5] = p1.y; w[6] = p1.z; w[7] = p1.w;
    }
    const float pb0 = pb[0];
    float acc[8] = {};

    const int start = offs[node], end = offs[node + 1];
    for (int k = start; k < end; k += 4) {
        const int idx = k + grp;
        const bool valid = idx < end;
        const int s = valid ? srcs[idx] : 0;
        u16x8 bv = *(const u16x8*)(Bmat + (size_t)s * 128 + c8);
        u16x8 lv = *(const u16x8*)(Lmat + (size_t)s * 128 + c8);

        float part = 0.f;
        #pragma unroll
        for (int j = 0; j < 8; ++j)
            part += fmaxf(a[j] + b2f(bv[j]), 0.f) * w[j];
        part += __shfl_xor(part, 8);
        part += __shfl_xor(part, 4);
        part += __shfl_xor(part, 2);
        part += __shfl_xor(part, 1);

        float pick = valid ? 1.f / (1.f + __expf(-(part + pb0))) : 0.f;
        #pragma unroll
        for (int j = 0; j < 8; ++j)
            acc[j] = fmaf(pick, b2f(lv[j]), acc[j]);
    }

    #pragma unroll
    for (int j = 0; j < 8; ++j) acc[j] += __shfl_xor(acc[j], 16);
    #pragma unroll
    for (int j = 0; j < 8; ++j) acc[j] += __shfl_xor(acc[j], 32);

    if (grp == 0) {
        u16x8 o;
        #pragma unroll
        for (int j = 0; j < 8; ++j) {
            float v = acc[j];
            if (RELU_OUT) v = fmaxf(v, 0.f);
            o[j] = f2b(v);
        }
        *(u16x8*)(out + (size_t)node * 128 + c8) = o;
    }
}

// ---- classifier: out[M,2] = h2(bf16) @ cls_w + cls_b (fp32) ----
__global__ __launch_bounds__(256) void classifier_bf16(
    const unsigned short* __restrict__ H, const float* __restrict__ Wc,
    const float* __restrict__ bc, float* __restrict__ out, int M)
{
    int m = blockIdx.x * 256 + threadIdx.x;
    if (m >= M) return;
    float a0 = bc[0], a1 = bc[1];
    for (int k = 0; k < 128; k += 8) {
        u16x8 h = *(const u16x8*)(H + (size_t)m * 128 + k);
        #pragma unroll
        for (int j = 0; j < 8; ++j) {
            float hv = b2f(h[j]);
            a0 = fmaf(hv, Wc[(k + j) * 2 + 0], a0);
            a1 = fmaf(hv, Wc[(k + j) * 2 + 1], a1);
        }
    }
    out[(size_t)m * 2 + 0] = a0;
    out[(size_t)m * 2 + 1] = a1;
}

extern "C" void kernel_launch(void* const* d_in, const int* in_sizes, int n_in,
                              void* d_out, int out_size, void* d_ws, size_t ws_size,
                              hipStream_t stream)
{
    const float* x      = (const float*)d_in[0];
    const int*   ei     = (const int*)d_in[1];
    const float* enc_w  = (const float*)d_in[2];
    const float* enc_b  = (const float*)d_in[3];
    const float* lin1_w = (const float*)d_in[4];
    const float* lin1_b = (const float*)d_in[5];
    const float* p1a_w  = (const float*)d_in[6];
    const float* p1a_b  = (const float*)d_in[7];
    const float* p1b_w  = (const float*)d_in[8];
    const float* p1b_b  = (const float*)d_in[9];
    const float* lin2_w = (const float*)d_in[10];
    const float* lin2_b = (const float*)d_in[11];
    const float* p2a_w  = (const float*)d_in[12];
    const float* p2a_b  = (const float*)d_in[13];
    const float* p2b_w  = (const float*)d_in[14];
    const float* p2b_b  = (const float*)d_in[15];
    const float* cls_w  = (const float*)d_in[16];
    const float* cls_b  = (const float*)d_in[17];

    const int M = N_NODES_C;
    const int E = in_sizes[1] / 2;
    const size_t HS = (size_t)M * HIDDEN;       // ushorts per node matrix

    unsigned short* Hb0 = (unsigned short*)d_ws;   // h0 -> A2 -> h2
    unsigned short* HA  = Hb0 + HS;                // A1 -> relu(h1)
    unsigned short* HB  = HA + HS;                 // B
    unsigned short* HL  = HB + HS;                 // L
    unsigned short* encT = HL + HS;                // [128][256]
    unsigned short* A1T = encT + 128 * 256;        // [128][128] each
    unsigned short* B1T = A1T + 128 * 128;
    unsigned short* L1T = B1T + 128 * 128;
    unsigned short* A2T = L1T + 128 * 128;
    unsigned short* B2T = A2T + 128 * 128;
    unsigned short* L2T = B2T + 128 * 128;
    int* deg   = (int*)(L2T + 128 * 128);          // M (reused as cursor)
    int* offs  = deg + M;                          // M+1
    int* srcs  = offs + M + 1;                     // E
    int* bsums = srcs + E;                         // ceil(M/1024) <= 64

    const int ggrid = (M + 63) / 64;
    const int egrid = (E + 255) / 256;
    const int ngrid = (M + 3) / 4;
    const int cgrid = (M + 255) / 256;
    const int sgrid = (M + 1023) / 1024;           // scan tiles (49)
    dim3 blk(256);

    // weight prep (independent)
    prep_weights<<<8, blk, 0, stream>>>(enc_w, p1a_w, lin1_w, p2a_w, lin2_w,
                                        encT, A1T, B1T, L1T, A2T, B2T, L2T);

    // CSR build (dst buckets, shared by both layers)
    hipMemsetAsync(deg, 0, (size_t)M * sizeof(int), stream);
    hist_kernel<<<egrid, blk, 0, stream>>>(ei, E, deg);
    scan_blocks<<<sgrid, blk, 0, stream>>>(deg, offs, bsums, M);
    scan_sums<<<1, 64, 0, stream>>>(bsums, offs, sgrid, M);
    scan_add<<<sgrid, blk, 0, stream>>>(offs, bsums, M);
    hipMemsetAsync(deg, 0, (size_t)M * sizeof(int), stream);
    scatter_kernel<<<egrid, blk, 0, stream>>>(ei, E, offs, deg, srcs);

    // encoder
    enc_mfma<<<ggrid, blk, 0, stream>>>(x, encT, enc_b, Hb0, M);

    // layer 1
    fused3_mfma<<<ggrid, blk, 0, stream>>>(Hb0, A1T, B1T, L1T, lin1_b,
                                           HA, HB, HL, M);
    gather_bf16<true><<<ngrid, blk, 0, stream>>>(offs, srcs, HA, HB, HL,
                                                 p1a_b, p1b_w, p1b_b, HA, M);

    // layer 2 (input = relu(h1) already applied at gather store)
    fused3_mfma<<<ggrid, blk, 0, stream>>>(HA, A2T, B2T, L2T, lin2_b,
                                           Hb0, HB, HL, M);
    gather_bf16<false><<<ngrid, blk, 0, stream>>>(offs, srcs, Hb0, HB, HL,
                                                  p2a_b, p2b_w, p2b_b, Hb0, M);

    // classifier
    classifier_bf16<<<cgrid, blk, 0, stream>>>(Hb0, cls_w, cls_b, (float*)d_out, M);
}